// Round 9
// baseline (414.536 us; speedup 1.0000x reference)
//
#include <hip/hip_runtime.h>
#include <math.h>

// PhaseNN on MI355X.  ROUND 20: R19 + A1 row-XOR swizzle restored.
// R19 post-mortem: 372 us; conflicts only 13.78M->8.92M (predicted <0.1M).
// Residual source: Phase-A A1 stores -- row stride 2048 == 0 mod 128 banks, so
// rows 0/1 alias and each wave's write dwords occupy 16 banks x4 writers
// (~4-way); 8.9M cyc/128CU/2.4GHz ~= 29 us.  R17's ^(row*5) unit swizzle was
// the fix all along (R17 measured 4K conflicts).
// R20 (single variable): A1 feat unit u=(w*4+j4) stored at u^(row2*5); GEMM1
// reads unit (F*4+q)^(row2*5).  XOR by 5 flips the 16-bank half-space between
// rows (disjoint); within a row j4*4+q covers 16 distinct banks; rp byte-pair
// shares a dword (merge, free).  Reads: 8 b128 addrs cover 32 banks once.
// Values bit-identical -> absmax must stay EXACTLY 0.015625.
// Structure: 128 blocks x 2 rows, 16 waves, i8 K=64 MFMA, 3 barriers/eval,
// T2 ct<36 LDS (144K) / ct>=36 global, T1 global.  Tripwire: WRITE > 5 MB.

typedef __attribute__((ext_vector_type(4))) float f32x4;
typedef __attribute__((ext_vector_type(4))) int   i32x4;
typedef __attribute__((ext_vector_type(8))) short bf16x8;
typedef __attribute__((ext_vector_type(2))) unsigned short u16x2;

struct TCons { float s[64]; float c[64]; };

__device__ __forceinline__ unsigned short f2bf(float f) {
  unsigned u = __builtin_bit_cast(unsigned, f);
  return (unsigned short)((u + 0x7FFFu + ((u >> 16) & 1u)) >> 16);
}
// pack 4 floats (|v|<=1) -> 4 i8 bytes scaled x127, LSB first
__device__ __forceinline__ int pk4i8(const float* v) {
  int a = __float2int_rn(v[0]*127.0f) & 255;
  int b = __float2int_rn(v[1]*127.0f) & 255;
  int c = __float2int_rn(v[2]*127.0f) & 255;
  int d = __float2int_rn(v[3]*127.0f);
  return a | (b << 8) | (c << 16) | (d << 24);
}

#define A1_OFF    0        // feats i8: 2 rows x [cos 1024 | sin 1024]; epilogue bf16 2x4096
#define MBUF_OFF  8192     // m partials i32: 2 kh x 2 rows x 132 (kh stride 1056)
#define W_OFF     10304    // w i8 (x127): 2 rows x 128 B = 256
#define ZP_OFF    10560    // 16 B zero page (bf16 epilogue pad cols)
#define XST_OFF   10576    // 2 rows x 104 chunks x 16 B bf16 (encoder prologue only)
#define T2L_OFF   13904    // T2 ct 0..35: 72 frag-pairs x 2048 B = 147456
#define RED_OFF   13904    // epilogue overlay (T2L dead by then): 16 KiB
#define LDS_BYTES 161360   // ~157.6 KiB of 160 KiB

__global__
__attribute__((amdgpu_flat_work_group_size(1024, 1024), amdgpu_waves_per_eu(4, 4)))
void phasenn_kernel(
    const float* __restrict__ x, const float* __restrict__ W_enc,
    const float* __restrict__ b_enc, const float* __restrict__ xi,
    const float* __restrict__ W_out, const float* __restrict__ b_out,
    float* __restrict__ dout, char* __restrict__ wsb, TCons tc)
{
  __shared__ __align__(16) char smem[LDS_BYTES];

  const int tid  = threadIdx.x;
  const int bk   = blockIdx.x;        // rows bk*2, bk*2+1
  const int w    = tid >> 6;          // 16 waves
  const int lane = tid & 63;
  const int q    = lane >> 4;
  const int b16  = lane & 15;         // MFMA col slot (batch row duplicated x8)
  const int row2 = b16 & 1;           // batch row within block
  const int j4   = b16 >> 2;          // lane's n-subtile j (0..3)
  const int rp   = (b16 >> 1) & 1;    // lane's r-pair (r = rp*2 + {0,1})
  const int swz5 = row2 * 5;          // A1 bank half-space flip

  char* T1g = wsb;                    // 256 KiB: (pt 8, F 16) frag-pairs, 2 planes x 1024
  char* T2g = wsb + (256 << 10);      // ct>=36: (ct*2+P2) frag-pairs, 2 planes x 1024

  // ---- LDS init: zero page only
  if (tid < 4) *(unsigned*)(smem + ZP_OFF + tid*4) = 0;

  // ---- xstage: x rows -> bf16 B-frag chunks (chunk ^ row), d>=784 zero (encoder)
  {
    const int row = tid >> 7, dg = tid & 127;
    if (row < 2 && dg < 100) {
      bf16x8 fr = {0,0,0,0,0,0,0,0};
      if (dg < 98) {
        f32x4 v0 = *(const f32x4*)(x + (bk*2 + row)*784 + dg*8);
        f32x4 v1 = *(const f32x4*)(x + (bk*2 + row)*784 + dg*8 + 4);
        #pragma unroll
        for (int i = 0; i < 8; ++i) fr[i] = (short)f2bf(i < 4 ? v0[i] : v1[i-4]);
      }
      *(bf16x8*)(smem + XST_OFF + row*1664 + (((dg ^ row) & 127) << 4)) = fr;
    }
  }

  // ---- table gen: i8 frag-pairs, plane layout (cos @ lane*16, sin @ +1024)
  if (w < 8) {  // T1: wave = ptile. lane: p = w*16+b16, n = F*64 + q*16 + i
    const int p = w*16 + b16;
    for (int F = 0; F < 16; ++F) {
      const int n0 = F*64 + q*16;
      f32x4 v0 = *(const f32x4*)(xi + p*1024 + n0);
      f32x4 v1 = *(const f32x4*)(xi + p*1024 + n0 + 4);
      f32x4 v2 = *(const f32x4*)(xi + p*1024 + n0 + 8);
      f32x4 v3 = *(const f32x4*)(xi + p*1024 + n0 + 12);
      float cv[16], sv[16];
      #pragma unroll
      for (int i = 0; i < 16; ++i) {
        float xv = (i < 4) ? v0[i] : (i < 8) ? v1[i-4] : (i < 12) ? v2[i-8] : v3[i-12];
        sv[i] = __sinf(xv); cv[i] = __cosf(xv);
      }
      i32x4 C = { pk4i8(cv), pk4i8(cv+4), pk4i8(cv+8), pk4i8(cv+12) };
      i32x4 S = { pk4i8(sv), pk4i8(sv+4), pk4i8(sv+8), pk4i8(sv+12) };
      char* dst = T1g + (size_t)(w*16 + F)*2048 + lane*16;
      *(i32x4*)(dst) = C; *(i32x4*)(dst + 1024) = S;
    }
  } else {      // T2: lane: n = ct*16+b16, p = P2*64 + q*16 + i
    const int w2 = w - 8;
    for (int f = 0; f < 16; ++f) {
      const int ct = w2*8 + (f >> 1), P2 = f & 1;
      const int n = ct*16 + b16;
      float cv[16], sv[16];
      #pragma unroll
      for (int i = 0; i < 16; ++i) {
        float xv = xi[(P2*64 + q*16 + i)*1024 + n];
        sv[i] = __sinf(xv); cv[i] = __cosf(xv);
      }
      i32x4 C = { pk4i8(cv), pk4i8(cv+4), pk4i8(cv+8), pk4i8(cv+12) };
      i32x4 S = { pk4i8(sv), pk4i8(sv+4), pk4i8(sv+8), pk4i8(sv+12) };
      char* dst = (ct < 36)
          ? (smem + T2L_OFF + (size_t)(ct*2 + P2)*2048 + lane*16)
          : (T2g + (size_t)(ct*2 + P2)*2048 + lane*16);
      *(i32x4*)(dst) = C; *(i32x4*)(dst + 1024) = S;
    }
  }
  __syncthreads();

  // ---- encoder (bf16 MFMA): unchanged.  Lane keeps 2 phases:
  // n = (w*4+j4)*16 + q*4 + rp*2 + {0,1}, batch row row2.
  float p0[2], ka[2], pwv[2];
  {
    f32x4 pac[4] = {{0,0,0,0},{0,0,0,0},{0,0,0,0},{0,0,0,0}};
    for (int kt = 0; kt < 25; ++kt) {
      const char* baddr =
          smem + XST_OFF + row2*1664 + ((((kt*4 + q) ^ row2) & 127) << 4);
      bf16x8 bfr = *(const bf16x8*)baddr;
      const int d = kt*32 + q*8;
      #pragma unroll
      for (int j = 0; j < 4; ++j) {
        bf16x8 afr = {0,0,0,0,0,0,0,0};
        if (d < 784) {
          const int n = (w*4 + j)*16 + b16;
          f32x4 v0 = *(const f32x4*)(W_enc + n*784 + d);
          f32x4 v1 = *(const f32x4*)(W_enc + n*784 + d + 4);
          #pragma unroll
          for (int i = 0; i < 8; ++i) afr[i] = (short)f2bf(i < 4 ? v0[i] : v1[i-4]);
        }
        pac[j] = __builtin_amdgcn_mfma_f32_16x16x32_bf16(afr, bfr, pac[j], 0, 0, 0);
      }
    }
    f32x4 pc = (j4==0) ? pac[0] : (j4==1) ? pac[1] : (j4==2) ? pac[2] : pac[3];
    float vA = rp ? pc[2] : pc[0];
    float vB = rp ? pc[3] : pc[1];
    const int n0 = (w*4 + j4)*16 + q*4 + rp*2;
    float ph0 = 6.283185307179586f / (1.0f + __expf(-(vA + b_enc[n0])));
    float ph1 = 6.283185307179586f / (1.0f + __expf(-(vB + b_enc[n0 + 1])));
    p0[0] = ph0; pwv[0] = ph0; ka[0] = 0.0f;
    p0[1] = ph1; pwv[1] = ph1; ka[1] = 0.0f;
  }

  const float dtf = 0.03125f, half = 0.015625f;
  const float sixth = (float)(0.03125/6.0);
  const float mscale = (float)(2.0 / (1024.0 * 16129.0));   // BETA/N / 127^2
  const float kscale = (float)(1.0 / 16129.0);              // 1/127^2

  for (int e = 0; e < 64; ++e) {
    float csv[2], snv[2];
    // ---- Phase A: all 64 lanes, 2 phases each; i8 feats, swizzled unit
    {
      #pragma unroll
      for (int r = 0; r < 2; ++r) {
        snv[r] = __sinf(pwv[r]);
        csv[r] = __cosf(pwv[r]);
      }
      int c0 = __float2int_rn(csv[0]*127.0f) & 255;
      int c1 = __float2int_rn(csv[1]*127.0f) & 255;
      int s0 = __float2int_rn(snv[0]*127.0f) & 255;
      int s1 = __float2int_rn(snv[1]*127.0f) & 255;
      const int su = (w*4 + j4) ^ swz5;
      char* base = smem + A1_OFF + row2*2048 + (su << 4) + q*4 + rp*2;
      *(unsigned short*)(base)        = (unsigned short)(c0 | (c1 << 8));
      *(unsigned short*)(base + 1024) = (unsigned short)(s0 | (s1 << 8));
    }
    __syncthreads();

    // ---- GEMM1 i8 K=64: m[p][row]; wave = (pt=w&7, kh=w>>3); 16 MFMA/wave
    {
      const int pt = w & 7, kh = w >> 3;
      i32x4 accC = {0,0,0,0}, accS = {0,0,0,0};
      const char* t1b = T1g + (size_t)(pt*16 + kh*8)*2048 + lane*16;
      const char* a1b = smem + A1_OFF + row2*2048;
      #pragma unroll
      for (int i2 = 0; i2 < 8; ++i2) {
        const int F = kh*8 + i2;
        i32x4 ca = *(const i32x4*)(t1b + (size_t)i2*2048);
        i32x4 sa = *(const i32x4*)(t1b + (size_t)i2*2048 + 1024);
        i32x4 bc = *(const i32x4*)(a1b + (((F*4 + q) ^ swz5) << 4));
        i32x4 bs = *(const i32x4*)(a1b + 1024 + (((F*4 + q) ^ swz5) << 4));
        accC = __builtin_amdgcn_mfma_i32_16x16x64_i8(ca, bc, accC, 0, 0, 0);
        accS = __builtin_amdgcn_mfma_i32_16x16x64_i8(sa, bs, accS, 0, 0, 0);
      }
      if (b16 < 2) {
        i32x4 acc = accC + accS;
        *(i32x4*)(smem + MBUF_OFF + kh*1056 + b16*528 + ((pt*16 + q*4) << 2)) = acc;
      }
    }
    __syncthreads();

    // ---- softmax (waves 0..1, wave = row): exact i32 m; w i8 (x127), linear
    if (w < 2) {
      const char* mb = smem + MBUF_OFF + w*528 + lane*8;
      int a0 = *(const int*)(mb),        a1 = *(const int*)(mb + 4);
      int b0 = *(const int*)(mb + 1056), b1 = *(const int*)(mb + 1056 + 4);
      float e0 = __expf((float)(a0 + b0) * mscale);
      float e1 = __expf((float)(a1 + b1) * mscale);
      float s = e0 + e1;
      #pragma unroll
      for (int off = 1; off < 64; off <<= 1) s += __shfl_xor(s, off, 64);
      const float inv = 127.0f / s;
      int w0 = __float2int_rn(e0 * inv);
      int w1 = __float2int_rn(e1 * inv);
      *(unsigned short*)(smem + W_OFF + w*128 + lane*2) =
          (unsigned short)((w0 & 255) | (w1 << 8));
    }
    __syncthreads();

    // ---- GEMM2 i8 K=64 + RK4: waves 0..8 read T2 from LDS, 9..15 global.
    // 4 ct x 2 P2 pairs = 16 MFMA/wave; lane selects (j4, rp); cached trig.
    {
      const float swt = tc.s[e], cwt = tc.c[e];
      const int st = e & 3;
      i32x4 wf0 = *(const i32x4*)(smem + W_OFF + row2*128 + q*16);
      i32x4 wf1 = *(const i32x4*)(smem + W_OFF + row2*128 + 64 + q*16);
      i32x4 aC[4] = {{0,0,0,0},{0,0,0,0},{0,0,0,0},{0,0,0,0}};
      i32x4 aS[4] = {{0,0,0,0},{0,0,0,0},{0,0,0,0},{0,0,0,0}};
      if (w < 9) {
        const char* t2b = smem + T2L_OFF + (size_t)(w*8)*2048 + lane*16;
        #pragma unroll
        for (int c = 0; c < 4; ++c)
          #pragma unroll
          for (int P2 = 0; P2 < 2; ++P2) {
            i32x4 ct_ = *(const i32x4*)(t2b + (size_t)(c*2 + P2)*2048);
            i32x4 st_ = *(const i32x4*)(t2b + (size_t)(c*2 + P2)*2048 + 1024);
            i32x4 wf = P2 ? wf1 : wf0;
            aC[c] = __builtin_amdgcn_mfma_i32_16x16x64_i8(ct_, wf, aC[c], 0, 0, 0);
            aS[c] = __builtin_amdgcn_mfma_i32_16x16x64_i8(st_, wf, aS[c], 0, 0, 0);
          }
      } else {
        const char* t2b = T2g + (size_t)(w*8)*2048 + lane*16;
        #pragma unroll
        for (int c = 0; c < 4; ++c)
          #pragma unroll
          for (int P2 = 0; P2 < 2; ++P2) {
            i32x4 ct_ = *(const i32x4*)(t2b + (size_t)(c*2 + P2)*2048);
            i32x4 st_ = *(const i32x4*)(t2b + (size_t)(c*2 + P2)*2048 + 1024);
            i32x4 wf = P2 ? wf1 : wf0;
            aC[c] = __builtin_amdgcn_mfma_i32_16x16x64_i8(ct_, wf, aC[c], 0, 0, 0);
            aS[c] = __builtin_amdgcn_mfma_i32_16x16x64_i8(st_, wf, aS[c], 0, 0, 0);
          }
      }
      i32x4 c4 = (j4==0) ? aC[0] : (j4==1) ? aC[1] : (j4==2) ? aC[2] : aC[3];
      i32x4 s4 = (j4==0) ? aS[0] : (j4==1) ? aS[1] : (j4==2) ? aS[2] : aS[3];
      float vC[2], vS[2];
      vC[0] = (float)(rp ? c4[2] : c4[0]);  vC[1] = (float)(rp ? c4[3] : c4[1]);
      vS[0] = (float)(rp ? s4[2] : s4[0]);  vS[1] = (float)(rp ? s4[3] : s4[1]);
      #pragma unroll
      for (int r = 0; r < 2; ++r) {
        float s_ = snv[r];
        float c_ = csv[r];
        float kv = (s_*vC[r] - c_*vS[r]) * kscale
                 + 0.08f*(swt*c_ - cwt*s_);            // A*sin(wt - phi)
        if (st == 0)      { ka[r]  = kv;           pwv[r] = p0[r] + kv*half; }
        else if (st == 1) { ka[r] += 2.0f*kv;      pwv[r] = p0[r] + kv*half; }
        else if (st == 2) { ka[r] += 2.0f*kv;      pwv[r] = p0[r] + kv*dtf;  }
        else { ka[r] += kv; p0[r] += ka[r]*sixth; pwv[r] = p0[r]; }
      }
    }
  }

  // ---- epilogue (bf16 MFMA): out = [cos phiT, sin phiT] @ W_out^T + b_out
  __syncthreads();
  {  // pack feats bf16 into A1 region (rows 0..1, 4-KB stride); all lanes, 2 each
    u16x2 cp, sp;
    #pragma unroll
    for (int r = 0; r < 2; ++r) {
      float ph = p0[r];
      cp[r] = f2bf(__cosf(ph)); sp[r] = f2bf(__sinf(ph));
    }
    const int cj = (w*4 + j4)*2 + (q >> 1);
    char* base = smem + A1_OFF + row2*4096 + ((q & 1) << 3) + rp*4;
    *(u16x2*)(base + ((cj ^ row2) << 4))        = cp;
    *(u16x2*)(base + ((cj ^ row2) << 4) + 2048) = sp;
  }
  __syncthreads();
  {  // D[cl][row] partial over this wave's 4 ktiles; A = W_out rows (cl<10, pad 0)
    f32x4 acc = {0.f, 0.f, 0.f, 0.f};
    #pragma unroll
    for (int i2 = 0; i2 < 4; ++i2) {
      const int kt = w*4 + i2;
      const int k = kt*32 + q*8;
      bf16x8 afr = {0,0,0,0,0,0,0,0};
      if (b16 < 10) {
        f32x4 v0 = *(const f32x4*)(W_out + b16*2048 + k);
        f32x4 v1 = *(const f32x4*)(W_out + b16*2048 + k + 4);
        #pragma unroll
        for (int i = 0; i < 8; ++i) afr[i] = (short)f2bf(i < 4 ? v0[i] : v1[i-4]);
      }
      const char* baddr = (b16 < 2)
          ? (smem + A1_OFF + b16*4096 + ((((kt*4 + q) ^ b16) & 255) << 4))
          : (smem + ZP_OFF);
      bf16x8 bfr = *(const bf16x8*)baddr;
      acc = __builtin_amdgcn_mfma_f32_16x16x32_bf16(afr, bfr, acc, 0, 0, 0);
    }
    *(f32x4*)(smem + RED_OFF + ((w*64 + lane) << 4)) = acc;
  }
  __syncthreads();
  if (tid < 64) {   // reduce 16 wave-partials; lane: row = tid&15, cl = (tid>>4)*4+r
    f32x4 s = {0.f, 0.f, 0.f, 0.f};
    #pragma unroll
    for (int w2 = 0; w2 < 16; ++w2)
      s += *(const f32x4*)(smem + RED_OFF + ((w2*64 + tid) << 4));
    const int b = tid & 15, q2 = tid >> 4;
    if (b < 2) {
      #pragma unroll
      for (int r = 0; r < 4; ++r) {
        const int cl = q2*4 + r;
        if (cl < 10)
          dout[(bk*2 + b)*10 + cl] = s[r] + b_out[cl];
      }
    }
  }
}

extern "C" void kernel_launch(void* const* d_in, const int* in_sizes, int n_in,
                              void* d_out, int out_size, void* d_ws, size_t ws_size,
                              hipStream_t stream) {
  (void)in_sizes; (void)n_in; (void)ws_size; (void)out_size;
  const float* x     = (const float*)d_in[0];
  const float* W_enc = (const float*)d_in[1];
  const float* b_enc = (const float*)d_in[2];
  const float* xi    = (const float*)d_in[3];
  const float* W_out = (const float*)d_in[4];
  const float* b_out = (const float*)d_in[5];
  float* out = (float*)d_out;
  char* wsb = (char*)d_ws;   // 512 KiB i8 tables; T1 + T2(ct>=36) rewritten per launch

  TCons tc;
  const double OME = 2.0 * 3.14159265358979323846 * 200.0;
  const double dtd = 0.03125;
  const double co[4] = {0.0, 0.5, 0.5, 1.0};
  for (int e = 0; e < 64; ++e) {
    double t = ((double)(e >> 2) + co[e & 3]) * dtd;
    tc.s[e] = (float)sin(OME * t);
    tc.c[e] = (float)cos(OME * t);
  }

  phasenn_kernel<<<dim3(128), dim3(1024), 0, stream>>>(
      x, W_enc, b_enc, xi, W_out, b_out, out, wsb, tc);
}

// Round 10
// 412.260 us; speedup vs baseline: 1.0055x; 1.0055x over previous
//
#include <hip/hip_runtime.h>
#include <math.h>

// PhaseNN on MI355X.  ROUND 21: R20 swizzle kept, spill removed.
// R20 post-mortem: conflicts 8.92M -> 4096 (swizzle correct) BUT WRITE 2956 ->
// 6540 KB + FETCH +1.8 MB at pinned VGPR=64 = scratch spill (R10/R14 signature):
// the non-affine XOR read address made the compiler materialize 8 ds_read
// addresses -> reg pressure -> spill ate the 29 us conflict win (372->378).
// R21 fix: XOR identity (F*4+q)^5 = (F^1)*4+(q^1) (q<4).  Swizzled read ==
// linear read with per-lane q->q^row2 and F->F^row2; F=kh*8+i2 -> F^row2 =
// i2+row2 (even i2) / i2-row2 (odd i2).  Two per-lane bases (a1E, a1O=a1E-
// row2*128) restore base+immediate for all 16 ds_reads.  Phase-A store addr
// hoisted (per-lane constant).  Placement/values/MFMA order bit-identical to
// R20 -> absmax must stay EXACTLY 0.015625.
// Verification signal: WRITE back to ~2.96 MB.  Tripwire: WRITE > 5 MB.
// Structure: 128 blocks x 2 rows, 16 waves, i8 K=64 MFMA, 3 barriers/eval,
// T2 ct<36 LDS (144K) / ct>=36 global, T1 global.

typedef __attribute__((ext_vector_type(4))) float f32x4;
typedef __attribute__((ext_vector_type(4))) int   i32x4;
typedef __attribute__((ext_vector_type(8))) short bf16x8;
typedef __attribute__((ext_vector_type(2))) unsigned short u16x2;

struct TCons { float s[64]; float c[64]; };

__device__ __forceinline__ unsigned short f2bf(float f) {
  unsigned u = __builtin_bit_cast(unsigned, f);
  return (unsigned short)((u + 0x7FFFu + ((u >> 16) & 1u)) >> 16);
}
// pack 4 floats (|v|<=1) -> 4 i8 bytes scaled x127, LSB first
__device__ __forceinline__ int pk4i8(const float* v) {
  int a = __float2int_rn(v[0]*127.0f) & 255;
  int b = __float2int_rn(v[1]*127.0f) & 255;
  int c = __float2int_rn(v[2]*127.0f) & 255;
  int d = __float2int_rn(v[3]*127.0f);
  return a | (b << 8) | (c << 16) | (d << 24);
}

#define A1_OFF    0        // feats i8: 2 rows x [cos 1024 | sin 1024]; epilogue bf16 2x4096
#define MBUF_OFF  8192     // m partials i32: 2 kh x 2 rows x 132 (kh stride 1056)
#define W_OFF     10304    // w i8 (x127): 2 rows x 128 B = 256
#define ZP_OFF    10560    // 16 B zero page (bf16 epilogue pad cols)
#define XST_OFF   10576    // 2 rows x 104 chunks x 16 B bf16 (encoder prologue only)
#define T2L_OFF   13904    // T2 ct 0..35: 72 frag-pairs x 2048 B = 147456
#define RED_OFF   13904    // epilogue overlay (T2L dead by then): 16 KiB
#define LDS_BYTES 161360   // ~157.6 KiB of 160 KiB

__global__
__attribute__((amdgpu_flat_work_group_size(1024, 1024), amdgpu_waves_per_eu(4, 4)))
void phasenn_kernel(
    const float* __restrict__ x, const float* __restrict__ W_enc,
    const float* __restrict__ b_enc, const float* __restrict__ xi,
    const float* __restrict__ W_out, const float* __restrict__ b_out,
    float* __restrict__ dout, char* __restrict__ wsb, TCons tc)
{
  __shared__ __align__(16) char smem[LDS_BYTES];

  const int tid  = threadIdx.x;
  const int bk   = blockIdx.x;        // rows bk*2, bk*2+1
  const int w    = tid >> 6;          // 16 waves
  const int lane = tid & 63;
  const int q    = lane >> 4;
  const int b16  = lane & 15;         // MFMA col slot (batch row duplicated x8)
  const int row2 = b16 & 1;           // batch row within block
  const int j4   = b16 >> 2;          // lane's n-subtile j (0..3)
  const int rp   = (b16 >> 1) & 1;    // lane's r-pair (r = rp*2 + {0,1})
  const int swz5 = row2 * 5;          // A1 bank half-space flip

  char* T1g = wsb;                    // 256 KiB: (pt 8, F 16) frag-pairs, 2 planes x 1024
  char* T2g = wsb + (256 << 10);      // ct>=36: (ct*2+P2) frag-pairs, 2 planes x 1024

  // ---- LDS init: zero page only
  if (tid < 4) *(unsigned*)(smem + ZP_OFF + tid*4) = 0;

  // ---- xstage: x rows -> bf16 B-frag chunks (chunk ^ row), d>=784 zero (encoder)
  {
    const int row = tid >> 7, dg = tid & 127;
    if (row < 2 && dg < 100) {
      bf16x8 fr = {0,0,0,0,0,0,0,0};
      if (dg < 98) {
        f32x4 v0 = *(const f32x4*)(x + (bk*2 + row)*784 + dg*8);
        f32x4 v1 = *(const f32x4*)(x + (bk*2 + row)*784 + dg*8 + 4);
        #pragma unroll
        for (int i = 0; i < 8; ++i) fr[i] = (short)f2bf(i < 4 ? v0[i] : v1[i-4]);
      }
      *(bf16x8*)(smem + XST_OFF + row*1664 + (((dg ^ row) & 127) << 4)) = fr;
    }
  }

  // ---- table gen: i8 frag-pairs, plane layout (cos @ lane*16, sin @ +1024)
  if (w < 8) {  // T1: wave = ptile. lane: p = w*16+b16, n = F*64 + q*16 + i
    const int p = w*16 + b16;
    for (int F = 0; F < 16; ++F) {
      const int n0 = F*64 + q*16;
      f32x4 v0 = *(const f32x4*)(xi + p*1024 + n0);
      f32x4 v1 = *(const f32x4*)(xi + p*1024 + n0 + 4);
      f32x4 v2 = *(const f32x4*)(xi + p*1024 + n0 + 8);
      f32x4 v3 = *(const f32x4*)(xi + p*1024 + n0 + 12);
      float cv[16], sv[16];
      #pragma unroll
      for (int i = 0; i < 16; ++i) {
        float xv = (i < 4) ? v0[i] : (i < 8) ? v1[i-4] : (i < 12) ? v2[i-8] : v3[i-12];
        sv[i] = __sinf(xv); cv[i] = __cosf(xv);
      }
      i32x4 C = { pk4i8(cv), pk4i8(cv+4), pk4i8(cv+8), pk4i8(cv+12) };
      i32x4 S = { pk4i8(sv), pk4i8(sv+4), pk4i8(sv+8), pk4i8(sv+12) };
      char* dst = T1g + (size_t)(w*16 + F)*2048 + lane*16;
      *(i32x4*)(dst) = C; *(i32x4*)(dst + 1024) = S;
    }
  } else {      // T2: lane: n = ct*16+b16, p = P2*64 + q*16 + i
    const int w2 = w - 8;
    for (int f = 0; f < 16; ++f) {
      const int ct = w2*8 + (f >> 1), P2 = f & 1;
      const int n = ct*16 + b16;
      float cv[16], sv[16];
      #pragma unroll
      for (int i = 0; i < 16; ++i) {
        float xv = xi[(P2*64 + q*16 + i)*1024 + n];
        sv[i] = __sinf(xv); cv[i] = __cosf(xv);
      }
      i32x4 C = { pk4i8(cv), pk4i8(cv+4), pk4i8(cv+8), pk4i8(cv+12) };
      i32x4 S = { pk4i8(sv), pk4i8(sv+4), pk4i8(sv+8), pk4i8(sv+12) };
      char* dst = (ct < 36)
          ? (smem + T2L_OFF + (size_t)(ct*2 + P2)*2048 + lane*16)
          : (T2g + (size_t)(ct*2 + P2)*2048 + lane*16);
      *(i32x4*)(dst) = C; *(i32x4*)(dst + 1024) = S;
    }
  }
  __syncthreads();

  // ---- encoder (bf16 MFMA): unchanged.  Lane keeps 2 phases:
  // n = (w*4+j4)*16 + q*4 + rp*2 + {0,1}, batch row row2.
  float p0[2], ka[2], pwv[2];
  {
    f32x4 pac[4] = {{0,0,0,0},{0,0,0,0},{0,0,0,0},{0,0,0,0}};
    for (int kt = 0; kt < 25; ++kt) {
      const char* baddr =
          smem + XST_OFF + row2*1664 + ((((kt*4 + q) ^ row2) & 127) << 4);
      bf16x8 bfr = *(const bf16x8*)baddr;
      const int d = kt*32 + q*8;
      #pragma unroll
      for (int j = 0; j < 4; ++j) {
        bf16x8 afr = {0,0,0,0,0,0,0,0};
        if (d < 784) {
          const int n = (w*4 + j)*16 + b16;
          f32x4 v0 = *(const f32x4*)(W_enc + n*784 + d);
          f32x4 v1 = *(const f32x4*)(W_enc + n*784 + d + 4);
          #pragma unroll
          for (int i = 0; i < 8; ++i) afr[i] = (short)f2bf(i < 4 ? v0[i] : v1[i-4]);
        }
        pac[j] = __builtin_amdgcn_mfma_f32_16x16x32_bf16(afr, bfr, pac[j], 0, 0, 0);
      }
    }
    f32x4 pc = (j4==0) ? pac[0] : (j4==1) ? pac[1] : (j4==2) ? pac[2] : pac[3];
    float vA = rp ? pc[2] : pc[0];
    float vB = rp ? pc[3] : pc[1];
    const int n0 = (w*4 + j4)*16 + q*4 + rp*2;
    float ph0 = 6.283185307179586f / (1.0f + __expf(-(vA + b_enc[n0])));
    float ph1 = 6.283185307179586f / (1.0f + __expf(-(vB + b_enc[n0 + 1])));
    p0[0] = ph0; pwv[0] = ph0; ka[0] = 0.0f;
    p0[1] = ph1; pwv[1] = ph1; ka[1] = 0.0f;
  }

  const float dtf = 0.03125f, half = 0.015625f;
  const float sixth = (float)(0.03125/6.0);
  const float mscale = (float)(2.0 / (1024.0 * 16129.0));   // BETA/N / 127^2
  const float kscale = (float)(1.0 / 16129.0);              // 1/127^2

  // ---- hoisted per-lane A1 addresses (constants across the eval loop):
  // store: unit u=(w*4+j4) placed at u^swz5.
  char* a1wr = smem + A1_OFF + row2*2048 + (((w*4 + j4) ^ swz5) << 4) + q*4 + rp*2;
  // GEMM1 read: swizzled unit (F*4+q)^swz5 == (F^row2)*4 + (q^row2); with
  // F = kh*8+i2: even i2 -> base a1E + i2*64, odd i2 -> a1O + i2*64.
  const int kh_ = w >> 3;
  const char* a1E = smem + A1_OFF + row2*2048 + ((q ^ row2) << 4) + row2*64 + kh_*512;
  const char* a1O = a1E - row2*128;

  for (int e = 0; e < 64; ++e) {
    float csv[2], snv[2];
    // ---- Phase A: all 64 lanes, 2 phases each; i8 feats, swizzled unit
    {
      #pragma unroll
      for (int r = 0; r < 2; ++r) {
        snv[r] = __sinf(pwv[r]);
        csv[r] = __cosf(pwv[r]);
      }
      int c0 = __float2int_rn(csv[0]*127.0f) & 255;
      int c1 = __float2int_rn(csv[1]*127.0f) & 255;
      int s0 = __float2int_rn(snv[0]*127.0f) & 255;
      int s1 = __float2int_rn(snv[1]*127.0f) & 255;
      *(unsigned short*)(a1wr)        = (unsigned short)(c0 | (c1 << 8));
      *(unsigned short*)(a1wr + 1024) = (unsigned short)(s0 | (s1 << 8));
    }
    __syncthreads();

    // ---- GEMM1 i8 K=64: m[p][row]; wave = (pt=w&7, kh=w>>3); 16 MFMA/wave;
    // reads via a1E/a1O bases + immediate offsets (spill-free swizzle).
    {
      const int pt = w & 7;
      i32x4 accC = {0,0,0,0}, accS = {0,0,0,0};
      const char* t1b = T1g + (size_t)(pt*16 + kh_*8)*2048 + lane*16;
      #pragma unroll
      for (int i2 = 0; i2 < 8; i2 += 2) {
        i32x4 ca0 = *(const i32x4*)(t1b + (size_t)i2*2048);
        i32x4 sa0 = *(const i32x4*)(t1b + (size_t)i2*2048 + 1024);
        i32x4 bc0 = *(const i32x4*)(a1E + i2*64);
        i32x4 bs0 = *(const i32x4*)(a1E + i2*64 + 1024);
        accC = __builtin_amdgcn_mfma_i32_16x16x64_i8(ca0, bc0, accC, 0, 0, 0);
        accS = __builtin_amdgcn_mfma_i32_16x16x64_i8(sa0, bs0, accS, 0, 0, 0);
        i32x4 ca1 = *(const i32x4*)(t1b + (size_t)(i2+1)*2048);
        i32x4 sa1 = *(const i32x4*)(t1b + (size_t)(i2+1)*2048 + 1024);
        i32x4 bc1 = *(const i32x4*)(a1O + (i2+1)*64);
        i32x4 bs1 = *(const i32x4*)(a1O + (i2+1)*64 + 1024);
        accC = __builtin_amdgcn_mfma_i32_16x16x64_i8(ca1, bc1, accC, 0, 0, 0);
        accS = __builtin_amdgcn_mfma_i32_16x16x64_i8(sa1, bs1, accS, 0, 0, 0);
      }
      if (b16 < 2) {
        i32x4 acc = accC + accS;
        *(i32x4*)(smem + MBUF_OFF + kh_*1056 + b16*528 + ((pt*16 + q*4) << 2)) = acc;
      }
    }
    __syncthreads();

    // ---- softmax (waves 0..1, wave = row): exact i32 m; w i8 (x127), linear
    if (w < 2) {
      const char* mb = smem + MBUF_OFF + w*528 + lane*8;
      int a0 = *(const int*)(mb),        a1 = *(const int*)(mb + 4);
      int b0 = *(const int*)(mb + 1056), b1 = *(const int*)(mb + 1056 + 4);
      float e0 = __expf((float)(a0 + b0) * mscale);
      float e1 = __expf((float)(a1 + b1) * mscale);
      float s = e0 + e1;
      #pragma unroll
      for (int off = 1; off < 64; off <<= 1) s += __shfl_xor(s, off, 64);
      const float inv = 127.0f / s;
      int w0 = __float2int_rn(e0 * inv);
      int w1 = __float2int_rn(e1 * inv);
      *(unsigned short*)(smem + W_OFF + w*128 + lane*2) =
          (unsigned short)((w0 & 255) | (w1 << 8));
    }
    __syncthreads();

    // ---- GEMM2 i8 K=64 + RK4: waves 0..8 read T2 from LDS, 9..15 global.
    // 4 ct x 2 P2 pairs = 16 MFMA/wave; lane selects (j4, rp); cached trig.
    {
      const float swt = tc.s[e], cwt = tc.c[e];
      const int st = e & 3;
      i32x4 wf0 = *(const i32x4*)(smem + W_OFF + row2*128 + q*16);
      i32x4 wf1 = *(const i32x4*)(smem + W_OFF + row2*128 + 64 + q*16);
      i32x4 aC[4] = {{0,0,0,0},{0,0,0,0},{0,0,0,0},{0,0,0,0}};
      i32x4 aS[4] = {{0,0,0,0},{0,0,0,0},{0,0,0,0},{0,0,0,0}};
      if (w < 9) {
        const char* t2b = smem + T2L_OFF + (size_t)(w*8)*2048 + lane*16;
        #pragma unroll
        for (int c = 0; c < 4; ++c)
          #pragma unroll
          for (int P2 = 0; P2 < 2; ++P2) {
            i32x4 ct_ = *(const i32x4*)(t2b + (size_t)(c*2 + P2)*2048);
            i32x4 st_ = *(const i32x4*)(t2b + (size_t)(c*2 + P2)*2048 + 1024);
            i32x4 wf = P2 ? wf1 : wf0;
            aC[c] = __builtin_amdgcn_mfma_i32_16x16x64_i8(ct_, wf, aC[c], 0, 0, 0);
            aS[c] = __builtin_amdgcn_mfma_i32_16x16x64_i8(st_, wf, aS[c], 0, 0, 0);
          }
      } else {
        const char* t2b = T2g + (size_t)(w*8)*2048 + lane*16;
        #pragma unroll
        for (int c = 0; c < 4; ++c)
          #pragma unroll
          for (int P2 = 0; P2 < 2; ++P2) {
            i32x4 ct_ = *(const i32x4*)(t2b + (size_t)(c*2 + P2)*2048);
            i32x4 st_ = *(const i32x4*)(t2b + (size_t)(c*2 + P2)*2048 + 1024);
            i32x4 wf = P2 ? wf1 : wf0;
            aC[c] = __builtin_amdgcn_mfma_i32_16x16x64_i8(ct_, wf, aC[c], 0, 0, 0);
            aS[c] = __builtin_amdgcn_mfma_i32_16x16x64_i8(st_, wf, aS[c], 0, 0, 0);
          }
      }
      i32x4 c4 = (j4==0) ? aC[0] : (j4==1) ? aC[1] : (j4==2) ? aC[2] : aC[3];
      i32x4 s4 = (j4==0) ? aS[0] : (j4==1) ? aS[1] : (j4==2) ? aS[2] : aS[3];
      float vC[2], vS[2];
      vC[0] = (float)(rp ? c4[2] : c4[0]);  vC[1] = (float)(rp ? c4[3] : c4[1]);
      vS[0] = (float)(rp ? s4[2] : s4[0]);  vS[1] = (float)(rp ? s4[3] : s4[1]);
      #pragma unroll
      for (int r = 0; r < 2; ++r) {
        float s_ = snv[r];
        float c_ = csv[r];
        float kv = (s_*vC[r] - c_*vS[r]) * kscale
                 + 0.08f*(swt*c_ - cwt*s_);            // A*sin(wt - phi)
        if (st == 0)      { ka[r]  = kv;           pwv[r] = p0[r] + kv*half; }
        else if (st == 1) { ka[r] += 2.0f*kv;      pwv[r] = p0[r] + kv*half; }
        else if (st == 2) { ka[r] += 2.0f*kv;      pwv[r] = p0[r] + kv*dtf;  }
        else { ka[r] += kv; p0[r] += ka[r]*sixth; pwv[r] = p0[r]; }
      }
    }
  }

  // ---- epilogue (bf16 MFMA): out = [cos phiT, sin phiT] @ W_out^T + b_out
  __syncthreads();
  {  // pack feats bf16 into A1 region (rows 0..1, 4-KB stride); all lanes, 2 each
    u16x2 cp, sp;
    #pragma unroll
    for (int r = 0; r < 2; ++r) {
      float ph = p0[r];
      cp[r] = f2bf(__cosf(ph)); sp[r] = f2bf(__sinf(ph));
    }
    const int cj = (w*4 + j4)*2 + (q >> 1);
    char* base = smem + A1_OFF + row2*4096 + ((q & 1) << 3) + rp*4;
    *(u16x2*)(base + ((cj ^ row2) << 4))        = cp;
    *(u16x2*)(base + ((cj ^ row2) << 4) + 2048) = sp;
  }
  __syncthreads();
  {  // D[cl][row] partial over this wave's 4 ktiles; A = W_out rows (cl<10, pad 0)
    f32x4 acc = {0.f, 0.f, 0.f, 0.f};
    #pragma unroll
    for (int i2 = 0; i2 < 4; ++i2) {
      const int kt = w*4 + i2;
      const int k = kt*32 + q*8;
      bf16x8 afr = {0,0,0,0,0,0,0,0};
      if (b16 < 10) {
        f32x4 v0 = *(const f32x4*)(W_out + b16*2048 + k);
        f32x4 v1 = *(const f32x4*)(W_out + b16*2048 + k + 4);
        #pragma unroll
        for (int i = 0; i < 8; ++i) afr[i] = (short)f2bf(i < 4 ? v0[i] : v1[i-4]);
      }
      const char* baddr = (b16 < 2)
          ? (smem + A1_OFF + b16*4096 + ((((kt*4 + q) ^ b16) & 255) << 4))
          : (smem + ZP_OFF);
      bf16x8 bfr = *(const bf16x8*)baddr;
      acc = __builtin_amdgcn_mfma_f32_16x16x32_bf16(afr, bfr, acc, 0, 0, 0);
    }
    *(f32x4*)(smem + RED_OFF + ((w*64 + lane) << 4)) = acc;
  }
  __syncthreads();
  if (tid < 64) {   // reduce 16 wave-partials; lane: row = tid&15, cl = (tid>>4)*4+r
    f32x4 s = {0.f, 0.f, 0.f, 0.f};
    #pragma unroll
    for (int w2 = 0; w2 < 16; ++w2)
      s += *(const f32x4*)(smem + RED_OFF + ((w2*64 + tid) << 4));
    const int b = tid & 15, q2 = tid >> 4;
    if (b < 2) {
      #pragma unroll
      for (int r = 0; r < 4; ++r) {
        const int cl = q2*4 + r;
        if (cl < 10)
          dout[(bk*2 + b)*10 + cl] = s[r] + b_out[cl];
      }
    }
  }
}

extern "C" void kernel_launch(void* const* d_in, const int* in_sizes, int n_in,
                              void* d_out, int out_size, void* d_ws, size_t ws_size,
                              hipStream_t stream) {
  (void)in_sizes; (void)n_in; (void)ws_size; (void)out_size;
  const float* x     = (const float*)d_in[0];
  const float* W_enc = (const float*)d_in[1];
  const float* b_enc = (const float*)d_in[2];
  const float* xi    = (const float*)d_in[3];
  const float* W_out = (const float*)d_in[4];
  const float* b_out = (const float*)d_in[5];
  float* out = (float*)d_out;
  char* wsb = (char*)d_ws;   // 512 KiB i8 tables; T1 + T2(ct>=36) rewritten per launch

  TCons tc;
  const double OME = 2.0 * 3.14159265358979323846 * 200.0;
  const double dtd = 0.03125;
  const double co[4] = {0.0, 0.5, 0.5, 1.0};
  for (int e = 0; e < 64; ++e) {
    double t = ((double)(e >> 2) + co[e & 3]) * dtd;
    tc.s[e] = (float)sin(OME * t);
    tc.c[e] = (float)cos(OME * t);
  }

  phasenn_kernel<<<dim3(128), dim3(1024), 0, stream>>>(
      x, W_enc, b_enc, xi, W_out, b_out, out, wsb, tc);
}

// Round 11
// 400.163 us; speedup vs baseline: 1.0359x; 1.0302x over previous
//
#include <hip/hip_runtime.h>
#include <math.h>

// PhaseNN on MI355X.  ROUND 22: 256 blocks x 1 row (fourth row-split).
// R21 post-mortem: spill fixed (WRITE 6540->2956) yet 379 us == R20; R19 (372)
// had 8.9M conflicts.  Neither conflicts nor spill were on the critical path ->
// eval loop is TABLE-STREAM-bound at the per-CU L1/L2 port (~60 B/cyc):
// eval ~14200 cyc = stream 368KB ~6100 + VALU ~3600 + MFMA ~2600 + barriers.
// Stream is irreducible (LDS full, each byte read once, VGPR pinned 64).
// R22 halves the VALU term and doubles CUs: 1 row/block, 256 blocks.
//  - 16-way col dup: lane owns 1 phase n = (w*4 + (b16>>2))*16 + q*4 + (b16&3).
//  - No row aliasing -> ALL swizzles dropped; GEMM1 feat reads are 16-lane
//    broadcasts (free); Phase A stores 1 cos + 1 sin byte per lane.
//  - softmax single wave; single W row read broadcast by all lanes.
// Arithmetic/quantization/summation order identical -> absmax EXACTLY 0.015625.
// Tripwire: WRITE > 5 MB = spill -> revert.
// Structure: i8 K=64 MFMA, 3 barriers/eval, T2 ct<36 LDS (144K) / ct>=36
// global, T1 global.

typedef __attribute__((ext_vector_type(4))) float f32x4;
typedef __attribute__((ext_vector_type(4))) int   i32x4;
typedef __attribute__((ext_vector_type(8))) short bf16x8;

struct TCons { float s[64]; float c[64]; };

__device__ __forceinline__ unsigned short f2bf(float f) {
  unsigned u = __builtin_bit_cast(unsigned, f);
  return (unsigned short)((u + 0x7FFFu + ((u >> 16) & 1u)) >> 16);
}
// pack 4 floats (|v|<=1) -> 4 i8 bytes scaled x127, LSB first
__device__ __forceinline__ int pk4i8(const float* v) {
  int a = __float2int_rn(v[0]*127.0f) & 255;
  int b = __float2int_rn(v[1]*127.0f) & 255;
  int c = __float2int_rn(v[2]*127.0f) & 255;
  int d = __float2int_rn(v[3]*127.0f);
  return a | (b << 8) | (c << 16) | (d << 24);
}

#define A1_OFF    0        // feats: GEMM1 i8 [cos 1024 | sin 1024]; epilogue bf16 [cos 2048 | sin 2048]
#define MBUF_OFF  4096     // m partials i32: 2 kh x 132 (kh stride 528) = 1056
#define W_OFF     5152     // w i8 (x127): 128 B (1 row)
#define ZP_OFF    5408     // 16 B zero page (bf16 epilogue pad cols)
#define XST_OFF   5424     // 104 chunks x 16 B bf16 (encoder prologue only)
#define T2L_OFF   7104     // T2 ct 0..35: 72 frag-pairs x 2048 B = 147456
#define RED_OFF   7104     // epilogue overlay (T2L dead by then): 16 KiB
#define LDS_BYTES 154560   // ~151 KiB of 160 KiB

__global__
__attribute__((amdgpu_flat_work_group_size(1024, 1024), amdgpu_waves_per_eu(4, 4)))
void phasenn_kernel(
    const float* __restrict__ x, const float* __restrict__ W_enc,
    const float* __restrict__ b_enc, const float* __restrict__ xi,
    const float* __restrict__ W_out, const float* __restrict__ b_out,
    float* __restrict__ dout, char* __restrict__ wsb, TCons tc)
{
  __shared__ __align__(16) char smem[LDS_BYTES];

  const int tid  = threadIdx.x;
  const int bk   = blockIdx.x;        // batch row bk
  const int w    = tid >> 6;          // 16 waves
  const int lane = tid & 63;
  const int q    = lane >> 4;
  const int b16  = lane & 15;         // MFMA col slot (batch row duplicated x16)
  const int j4   = b16 >> 2;          // lane's n-subtile j / GEMM2 ct select
  const int r4   = b16 & 3;           // lane's r within the D reg quad
  const int nph  = (w*4 + j4)*16 + q*4 + r4;   // the ONE phase this lane owns

  char* T1g = wsb;                    // 256 KiB: (pt 8, F 16) frag-pairs, 2 planes x 1024
  char* T2g = wsb + (256 << 10);      // ct>=36: (ct*2+P2) frag-pairs, 2 planes x 1024

  // ---- LDS init: zero page only
  if (tid < 4) *(unsigned*)(smem + ZP_OFF + tid*4) = 0;

  // ---- xstage: x row bk -> bf16 B-frag chunks (linear), d>=784 zero (encoder)
  if (tid < 100) {
    const int dg = tid;
    bf16x8 fr = {0,0,0,0,0,0,0,0};
    if (dg < 98) {
      f32x4 v0 = *(const f32x4*)(x + (size_t)bk*784 + dg*8);
      f32x4 v1 = *(const f32x4*)(x + (size_t)bk*784 + dg*8 + 4);
      #pragma unroll
      for (int i = 0; i < 8; ++i) fr[i] = (short)f2bf(i < 4 ? v0[i] : v1[i-4]);
    }
    *(bf16x8*)(smem + XST_OFF + (dg << 4)) = fr;
  }

  // ---- table gen: i8 frag-pairs, plane layout (cos @ lane*16, sin @ +1024)
  if (w < 8) {  // T1: wave = ptile. lane: p = w*16+b16, n = F*64 + q*16 + i
    const int p = w*16 + b16;
    for (int F = 0; F < 16; ++F) {
      const int n0 = F*64 + q*16;
      f32x4 v0 = *(const f32x4*)(xi + p*1024 + n0);
      f32x4 v1 = *(const f32x4*)(xi + p*1024 + n0 + 4);
      f32x4 v2 = *(const f32x4*)(xi + p*1024 + n0 + 8);
      f32x4 v3 = *(const f32x4*)(xi + p*1024 + n0 + 12);
      float cv[16], sv[16];
      #pragma unroll
      for (int i = 0; i < 16; ++i) {
        float xv = (i < 4) ? v0[i] : (i < 8) ? v1[i-4] : (i < 12) ? v2[i-8] : v3[i-12];
        sv[i] = __sinf(xv); cv[i] = __cosf(xv);
      }
      i32x4 C = { pk4i8(cv), pk4i8(cv+4), pk4i8(cv+8), pk4i8(cv+12) };
      i32x4 S = { pk4i8(sv), pk4i8(sv+4), pk4i8(sv+8), pk4i8(sv+12) };
      char* dst = T1g + (size_t)(w*16 + F)*2048 + lane*16;
      *(i32x4*)(dst) = C; *(i32x4*)(dst + 1024) = S;
    }
  } else {      // T2: lane: n = ct*16+b16, p = P2*64 + q*16 + i
    const int w2 = w - 8;
    for (int f = 0; f < 16; ++f) {
      const int ct = w2*8 + (f >> 1), P2 = f & 1;
      const int n = ct*16 + b16;
      float cv[16], sv[16];
      #pragma unroll
      for (int i = 0; i < 16; ++i) {
        float xv = xi[(P2*64 + q*16 + i)*1024 + n];
        sv[i] = __sinf(xv); cv[i] = __cosf(xv);
      }
      i32x4 C = { pk4i8(cv), pk4i8(cv+4), pk4i8(cv+8), pk4i8(cv+12) };
      i32x4 S = { pk4i8(sv), pk4i8(sv+4), pk4i8(sv+8), pk4i8(sv+12) };
      char* dst = (ct < 36)
          ? (smem + T2L_OFF + (size_t)(ct*2 + P2)*2048 + lane*16)
          : (T2g + (size_t)(ct*2 + P2)*2048 + lane*16);
      *(i32x4*)(dst) = C; *(i32x4*)(dst + 1024) = S;
    }
  }
  __syncthreads();

  // ---- encoder (bf16 MFMA): B cols all duplicate row bk; lane keeps 1 phase:
  // pac[j4] reg r4 -> phase nph.
  float p0, ka, pwv;
  {
    f32x4 pac[4] = {{0,0,0,0},{0,0,0,0},{0,0,0,0},{0,0,0,0}};
    for (int kt = 0; kt < 25; ++kt) {
      bf16x8 bfr = *(const bf16x8*)(smem + XST_OFF + ((kt*4 + q) << 4));
      const int d = kt*32 + q*8;
      #pragma unroll
      for (int j = 0; j < 4; ++j) {
        bf16x8 afr = {0,0,0,0,0,0,0,0};
        if (d < 784) {
          const int n = (w*4 + j)*16 + b16;
          f32x4 v0 = *(const f32x4*)(W_enc + n*784 + d);
          f32x4 v1 = *(const f32x4*)(W_enc + n*784 + d + 4);
          #pragma unroll
          for (int i = 0; i < 8; ++i) afr[i] = (short)f2bf(i < 4 ? v0[i] : v1[i-4]);
        }
        pac[j] = __builtin_amdgcn_mfma_f32_16x16x32_bf16(afr, bfr, pac[j], 0, 0, 0);
      }
    }
    f32x4 pc = (j4==0) ? pac[0] : (j4==1) ? pac[1] : (j4==2) ? pac[2] : pac[3];
    float vA = (r4==0) ? pc[0] : (r4==1) ? pc[1] : (r4==2) ? pc[2] : pc[3];
    float ph = 6.283185307179586f / (1.0f + __expf(-(vA + b_enc[nph])));
    p0 = ph; pwv = ph; ka = 0.0f;
  }

  const float dtf = 0.03125f, half = 0.015625f;
  const float sixth = (float)(0.03125/6.0);
  const float mscale = (float)(2.0 / (1024.0 * 16129.0));   // BETA/N / 127^2
  const float kscale = (float)(1.0 / 16129.0);              // 1/127^2

  char* a1wr = smem + A1_OFF + nph;   // per-lane feat byte address (constant)

  for (int e = 0; e < 64; ++e) {
    float csv, snv;
    // ---- Phase A: all 64 lanes, 1 phase each; 1 cos + 1 sin byte store
    {
      snv = __sinf(pwv);
      csv = __cosf(pwv);
      *(char*)(a1wr)        = (char)(__float2int_rn(csv*127.0f));
      *(char*)(a1wr + 1024) = (char)(__float2int_rn(snv*127.0f));
    }
    __syncthreads();

    // ---- GEMM1 i8 K=64: m[p]; wave = (pt=w&7, kh=w>>3); 16 MFMA/wave;
    // feat reads are 16-lane broadcasts (addr depends on q only).
    {
      const int pt = w & 7, kh = w >> 3;
      i32x4 accC = {0,0,0,0}, accS = {0,0,0,0};
      const char* t1b = T1g + (size_t)(pt*16 + kh*8)*2048 + lane*16;
      const char* a1b = smem + A1_OFF + kh*512 + q*16;
      #pragma unroll
      for (int i2 = 0; i2 < 8; ++i2) {
        i32x4 ca = *(const i32x4*)(t1b + (size_t)i2*2048);
        i32x4 sa = *(const i32x4*)(t1b + (size_t)i2*2048 + 1024);
        i32x4 bc = *(const i32x4*)(a1b + i2*64);
        i32x4 bs = *(const i32x4*)(a1b + i2*64 + 1024);
        accC = __builtin_amdgcn_mfma_i32_16x16x64_i8(ca, bc, accC, 0, 0, 0);
        accS = __builtin_amdgcn_mfma_i32_16x16x64_i8(sa, bs, accS, 0, 0, 0);
      }
      if (b16 == 0) {
        i32x4 acc = accC + accS;
        *(i32x4*)(smem + MBUF_OFF + kh*528 + ((pt*16 + q*4) << 2)) = acc;
      }
    }
    __syncthreads();

    // ---- softmax (wave 0): exact i32 m; w i8 (x127), single 128-B row
    if (w == 0) {
      const char* mb = smem + MBUF_OFF + lane*8;
      int a0 = *(const int*)(mb),       a1 = *(const int*)(mb + 4);
      int b0 = *(const int*)(mb + 528), b1 = *(const int*)(mb + 528 + 4);
      float e0 = __expf((float)(a0 + b0) * mscale);
      float e1 = __expf((float)(a1 + b1) * mscale);
      float s = e0 + e1;
      #pragma unroll
      for (int off = 1; off < 64; off <<= 1) s += __shfl_xor(s, off, 64);
      const float inv = 127.0f / s;
      int w0 = __float2int_rn(e0 * inv);
      int w1 = __float2int_rn(e1 * inv);
      *(unsigned short*)(smem + W_OFF + lane*2) =
          (unsigned short)((w0 & 255) | (w1 << 8));
    }
    __syncthreads();

    // ---- GEMM2 i8 K=64 + RK4: waves 0..8 read T2 from LDS, 9..15 global.
    // wave ct = w*4 + c; lane selects (c=j4, reg=r4); cached trig.
    {
      const float swt = tc.s[e], cwt = tc.c[e];
      const int st = e & 3;
      i32x4 wf0 = *(const i32x4*)(smem + W_OFF + q*16);
      i32x4 wf1 = *(const i32x4*)(smem + W_OFF + 64 + q*16);
      i32x4 aC[4] = {{0,0,0,0},{0,0,0,0},{0,0,0,0},{0,0,0,0}};
      i32x4 aS[4] = {{0,0,0,0},{0,0,0,0},{0,0,0,0},{0,0,0,0}};
      if (w < 9) {
        const char* t2b = smem + T2L_OFF + (size_t)(w*8)*2048 + lane*16;
        #pragma unroll
        for (int c = 0; c < 4; ++c)
          #pragma unroll
          for (int P2 = 0; P2 < 2; ++P2) {
            i32x4 ct_ = *(const i32x4*)(t2b + (size_t)(c*2 + P2)*2048);
            i32x4 st_ = *(const i32x4*)(t2b + (size_t)(c*2 + P2)*2048 + 1024);
            i32x4 wf = P2 ? wf1 : wf0;
            aC[c] = __builtin_amdgcn_mfma_i32_16x16x64_i8(ct_, wf, aC[c], 0, 0, 0);
            aS[c] = __builtin_amdgcn_mfma_i32_16x16x64_i8(st_, wf, aS[c], 0, 0, 0);
          }
      } else {
        const char* t2b = T2g + (size_t)(w*8)*2048 + lane*16;
        #pragma unroll
        for (int c = 0; c < 4; ++c)
          #pragma unroll
          for (int P2 = 0; P2 < 2; ++P2) {
            i32x4 ct_ = *(const i32x4*)(t2b + (size_t)(c*2 + P2)*2048);
            i32x4 st_ = *(const i32x4*)(t2b + (size_t)(c*2 + P2)*2048 + 1024);
            i32x4 wf = P2 ? wf1 : wf0;
            aC[c] = __builtin_amdgcn_mfma_i32_16x16x64_i8(ct_, wf, aC[c], 0, 0, 0);
            aS[c] = __builtin_amdgcn_mfma_i32_16x16x64_i8(st_, wf, aS[c], 0, 0, 0);
          }
      }
      i32x4 c4 = (j4==0) ? aC[0] : (j4==1) ? aC[1] : (j4==2) ? aC[2] : aC[3];
      i32x4 s4 = (j4==0) ? aS[0] : (j4==1) ? aS[1] : (j4==2) ? aS[2] : aS[3];
      float vC = (float)((r4==0) ? c4[0] : (r4==1) ? c4[1] : (r4==2) ? c4[2] : c4[3]);
      float vS = (float)((r4==0) ? s4[0] : (r4==1) ? s4[1] : (r4==2) ? s4[2] : s4[3]);
      float kv = (snv*vC - csv*vS) * kscale
               + 0.08f*(swt*csv - cwt*snv);           // A*sin(wt - phi)
      if (st == 0)      { ka  = kv;           pwv = p0 + kv*half; }
      else if (st == 1) { ka += 2.0f*kv;      pwv = p0 + kv*half; }
      else if (st == 2) { ka += 2.0f*kv;      pwv = p0 + kv*dtf;  }
      else { ka += kv; p0 += ka*sixth; pwv = p0; }
    }
  }

  // ---- epilogue (bf16 MFMA): out = [cos phiT, sin phiT] @ W_out^T + b_out
  __syncthreads();
  {  // pack feats bf16: cos @ A1 + n*2, sin @ A1 + 2048 + n*2 (1 each per lane)
    *(unsigned short*)(smem + A1_OFF + nph*2)        = f2bf(__cosf(p0));
    *(unsigned short*)(smem + A1_OFF + 2048 + nph*2) = f2bf(__sinf(p0));
  }
  __syncthreads();
  {  // D[cl][col] partial over this wave's 4 ktiles; A = W_out rows (cl<10, pad 0)
    f32x4 acc = {0.f, 0.f, 0.f, 0.f};
    #pragma unroll
    for (int i2 = 0; i2 < 4; ++i2) {
      const int kt = w*4 + i2;
      const int k = kt*32 + q*8;
      bf16x8 afr = {0,0,0,0,0,0,0,0};
      if (b16 < 10) {
        f32x4 v0 = *(const f32x4*)(W_out + b16*2048 + k);
        f32x4 v1 = *(const f32x4*)(W_out + b16*2048 + k + 4);
        #pragma unroll
        for (int i = 0; i < 8; ++i) afr[i] = (short)f2bf(i < 4 ? v0[i] : v1[i-4]);
      }
      const char* baddr = (b16 == 0)
          ? (smem + A1_OFF + ((kt*4 + q) << 4))
          : (smem + ZP_OFF);
      bf16x8 bfr = *(const bf16x8*)baddr;
      acc = __builtin_amdgcn_mfma_f32_16x16x32_bf16(afr, bfr, acc, 0, 0, 0);
    }
    *(f32x4*)(smem + RED_OFF + ((w*64 + lane) << 4)) = acc;
  }
  __syncthreads();
  if (tid < 64) {   // reduce 16 wave-partials; lane: col = tid&15, cl = (tid>>4)*4+r
    f32x4 s = {0.f, 0.f, 0.f, 0.f};
    #pragma unroll
    for (int w2 = 0; w2 < 16; ++w2)
      s += *(const f32x4*)(smem + RED_OFF + ((w2*64 + tid) << 4));
    const int b = tid & 15, q2 = tid >> 4;
    if (b == 0) {
      #pragma unroll
      for (int r = 0; r < 4; ++r) {
        const int cl = q2*4 + r;
        if (cl < 10)
          dout[(size_t)bk*10 + cl] = s[r] + b_out[cl];
      }
    }
  }
}

extern "C" void kernel_launch(void* const* d_in, const int* in_sizes, int n_in,
                              void* d_out, int out_size, void* d_ws, size_t ws_size,
                              hipStream_t stream) {
  (void)in_sizes; (void)n_in; (void)ws_size; (void)out_size;
  const float* x     = (const float*)d_in[0];
  const float* W_enc = (const float*)d_in[1];
  const float* b_enc = (const float*)d_in[2];
  const float* xi    = (const float*)d_in[3];
  const float* W_out = (const float*)d_in[4];
  const float* b_out = (const float*)d_in[5];
  float* out = (float*)d_out;
  char* wsb = (char*)d_ws;   // 512 KiB i8 tables; T1 + T2(ct>=36) rewritten per launch

  TCons tc;
  const double OME = 2.0 * 3.14159265358979323846 * 200.0;
  const double dtd = 0.03125;
  const double co[4] = {0.0, 0.5, 0.5, 1.0};
  for (int e = 0; e < 64; ++e) {
    double t = ((double)(e >> 2) + co[e & 3]) * dtd;
    tc.s[e] = (float)sin(OME * t);
    tc.c[e] = (float)cos(OME * t);
  }

  phasenn_kernel<<<dim3(256), dim3(1024), 0, stream>>>(
      x, W_enc, b_enc, xi, W_out, b_out, out, wsb, tc);
}

// Round 12
// 348.666 us; speedup vs baseline: 1.1889x; 1.1477x over previous
//
#include <hip/hip_runtime.h>
#include <math.h>

// PhaseNN on MI355X.  ROUND 23: T1 table -> i4 nibbles (stream 368->240 KB/eval).
// R22 post-mortem: 256 blocks at same wall time as 128 -- per-CU eval (~14500cy)
// is TABLE-STREAM-bound and stream is per-CU invariant; 256 CUs x ~56 B/cyc hit
// the ~34 TB/s L2 aggregate cap.  Only remaining lever: fewer table bytes.
// R23: T1 (softmax side only; GEMM2 stays i8) packed as i4, scale x7, BIAS +8:
//  - u = round(cos*7)+8 in [1,15]; two nibbles/byte; frag = [cos 8B | sin 8B]
//    per lane (one dwordx4 load), frag stride 1024 B; T1 = 128 KB.
//  - Unpack = AND/SHR only (u unsigned; SWAR sign-extend would borrow across
//    bytes).  mfma_i32 i8 sees bytes 1..15; bias adds 8*Sum(f) to EVERY m_p
//    equally and softmax is shift-invariant -> results equivalent.
//  - mscale = 2/(1024*7*127).  GEMM2/W/feats/epilogue untouched.
// Accuracy: d(softmax arg) ~ 0.002 (damped by BETA/N) -> absmax may shift to
// ~0.02; fail => revert T1 to i8.  Tripwire: WRITE > 5 MB = spill.
// Structure: 256 blocks x 1 row, 16 waves, i8 K=64 MFMA, 3 barriers/eval,
// T2 ct<36 LDS (144K) / ct>=36 global, T1 global (i4).

typedef __attribute__((ext_vector_type(4))) float f32x4;
typedef __attribute__((ext_vector_type(4))) int   i32x4;
typedef __attribute__((ext_vector_type(8))) short bf16x8;

struct TCons { float s[64]; float c[64]; };

__device__ __forceinline__ unsigned short f2bf(float f) {
  unsigned u = __builtin_bit_cast(unsigned, f);
  return (unsigned short)((u + 0x7FFFu + ((u >> 16) & 1u)) >> 16);
}
// pack 4 floats (|v|<=1) -> 4 i8 bytes scaled x127, LSB first
__device__ __forceinline__ int pk4i8(const float* v) {
  int a = __float2int_rn(v[0]*127.0f) & 255;
  int b = __float2int_rn(v[1]*127.0f) & 255;
  int c = __float2int_rn(v[2]*127.0f) & 255;
  int d = __float2int_rn(v[3]*127.0f);
  return a | (b << 8) | (c << 16) | (d << 24);
}

#define A1_OFF    0        // feats: GEMM1 i8 [cos 1024 | sin 1024]; epilogue bf16 [cos 2048 | sin 2048]
#define MBUF_OFF  4096     // m partials i32: 2 kh x 132 (kh stride 528) = 1056
#define W_OFF     5152     // w i8 (x127): 128 B (1 row)
#define ZP_OFF    5408     // 16 B zero page (bf16 epilogue pad cols)
#define XST_OFF   5424     // 104 chunks x 16 B bf16 (encoder prologue only)
#define T2L_OFF   7104     // T2 ct 0..35: 72 frag-pairs x 2048 B = 147456
#define RED_OFF   7104     // epilogue overlay (T2L dead by then): 16 KiB
#define LDS_BYTES 154560   // ~151 KiB of 160 KiB

__global__
__attribute__((amdgpu_flat_work_group_size(1024, 1024), amdgpu_waves_per_eu(4, 4)))
void phasenn_kernel(
    const float* __restrict__ x, const float* __restrict__ W_enc,
    const float* __restrict__ b_enc, const float* __restrict__ xi,
    const float* __restrict__ W_out, const float* __restrict__ b_out,
    float* __restrict__ dout, char* __restrict__ wsb, TCons tc)
{
  __shared__ __align__(16) char smem[LDS_BYTES];

  const int tid  = threadIdx.x;
  const int bk   = blockIdx.x;        // batch row bk
  const int w    = tid >> 6;          // 16 waves
  const int lane = tid & 63;
  const int q    = lane >> 4;
  const int b16  = lane & 15;         // MFMA col slot (batch row duplicated x16)
  const int j4   = b16 >> 2;          // lane's n-subtile j / GEMM2 ct select
  const int r4   = b16 & 3;           // lane's r within the D reg quad
  const int nph  = (w*4 + j4)*16 + q*4 + r4;   // the ONE phase this lane owns

  char* T1g = wsb;                    // 128 KiB: (pt 8, F 16) i4 frags x 64 lanes x 16 B
  char* T2g = wsb + (256 << 10);      // ct>=36: (ct*2+P2) frag-pairs, 2 planes x 1024 (i8)

  // ---- LDS init: zero page only
  if (tid < 4) *(unsigned*)(smem + ZP_OFF + tid*4) = 0;

  // ---- xstage: x row bk -> bf16 B-frag chunks (linear), d>=784 zero (encoder)
  if (tid < 100) {
    const int dg = tid;
    bf16x8 fr = {0,0,0,0,0,0,0,0};
    if (dg < 98) {
      f32x4 v0 = *(const f32x4*)(x + (size_t)bk*784 + dg*8);
      f32x4 v1 = *(const f32x4*)(x + (size_t)bk*784 + dg*8 + 4);
      #pragma unroll
      for (int i = 0; i < 8; ++i) fr[i] = (short)f2bf(i < 4 ? v0[i] : v1[i-4]);
    }
    *(bf16x8*)(smem + XST_OFF + (dg << 4)) = fr;
  }

  // ---- table gen
  if (w < 8) {  // T1 i4: lane: p = w*16+b16, n = F*64 + q*16 + i; u = c*7+8
    const int p = w*16 + b16;
    for (int F = 0; F < 16; ++F) {
      const int n0 = F*64 + q*16;
      f32x4 v0 = *(const f32x4*)(xi + p*1024 + n0);
      f32x4 v1 = *(const f32x4*)(xi + p*1024 + n0 + 4);
      f32x4 v2 = *(const f32x4*)(xi + p*1024 + n0 + 8);
      f32x4 v3 = *(const f32x4*)(xi + p*1024 + n0 + 12);
      int cu[16], su[16];
      #pragma unroll
      for (int i = 0; i < 16; ++i) {
        float xv = (i < 4) ? v0[i] : (i < 8) ? v1[i-4] : (i < 12) ? v2[i-8] : v3[i-12];
        su[i] = __float2int_rn(__sinf(xv)*7.0f) + 8;   // 1..15
        cu[i] = __float2int_rn(__cosf(xv)*7.0f) + 8;
      }
      // pack: dword d covers k-group d*8; byte i = u[g+i] | u[g+i+4]<<4
      unsigned pc0=0, pc1=0, ps0=0, ps1=0;
      #pragma unroll
      for (int i = 0; i < 4; ++i) {
        pc0 |= (unsigned)(cu[i]     | (cu[i+4]  << 4)) << (8*i);
        pc1 |= (unsigned)(cu[8+i]   | (cu[12+i] << 4)) << (8*i);
        ps0 |= (unsigned)(su[i]     | (su[i+4]  << 4)) << (8*i);
        ps1 |= (unsigned)(su[8+i]   | (su[12+i] << 4)) << (8*i);
      }
      i32x4 P = {(int)pc0, (int)pc1, (int)ps0, (int)ps1};
      *(i32x4*)(T1g + (size_t)(w*16 + F)*1024 + lane*16) = P;
    }
  } else {      // T2 i8 (unchanged): lane: n = ct*16+b16, p = P2*64 + q*16 + i
    const int w2 = w - 8;
    for (int f = 0; f < 16; ++f) {
      const int ct = w2*8 + (f >> 1), P2 = f & 1;
      const int n = ct*16 + b16;
      float cv[16], sv[16];
      #pragma unroll
      for (int i = 0; i < 16; ++i) {
        float xv = xi[(P2*64 + q*16 + i)*1024 + n];
        sv[i] = __sinf(xv); cv[i] = __cosf(xv);
      }
      i32x4 C = { pk4i8(cv), pk4i8(cv+4), pk4i8(cv+8), pk4i8(cv+12) };
      i32x4 S = { pk4i8(sv), pk4i8(sv+4), pk4i8(sv+8), pk4i8(sv+12) };
      char* dst = (ct < 36)
          ? (smem + T2L_OFF + (size_t)(ct*2 + P2)*2048 + lane*16)
          : (T2g + (size_t)(ct*2 + P2)*2048 + lane*16);
      *(i32x4*)(dst) = C; *(i32x4*)(dst + 1024) = S;
    }
  }
  __syncthreads();

  // ---- encoder (bf16 MFMA): B cols all duplicate row bk; lane keeps 1 phase.
  float p0, ka, pwv;
  {
    f32x4 pac[4] = {{0,0,0,0},{0,0,0,0},{0,0,0,0},{0,0,0,0}};
    for (int kt = 0; kt < 25; ++kt) {
      bf16x8 bfr = *(const bf16x8*)(smem + XST_OFF + ((kt*4 + q) << 4));
      const int d = kt*32 + q*8;
      #pragma unroll
      for (int j = 0; j < 4; ++j) {
        bf16x8 afr = {0,0,0,0,0,0,0,0};
        if (d < 784) {
          const int n = (w*4 + j)*16 + b16;
          f32x4 v0 = *(const f32x4*)(W_enc + n*784 + d);
          f32x4 v1 = *(const f32x4*)(W_enc + n*784 + d + 4);
          #pragma unroll
          for (int i = 0; i < 8; ++i) afr[i] = (short)f2bf(i < 4 ? v0[i] : v1[i-4]);
        }
        pac[j] = __builtin_amdgcn_mfma_f32_16x16x32_bf16(afr, bfr, pac[j], 0, 0, 0);
      }
    }
    f32x4 pc = (j4==0) ? pac[0] : (j4==1) ? pac[1] : (j4==2) ? pac[2] : pac[3];
    float vA = (r4==0) ? pc[0] : (r4==1) ? pc[1] : (r4==2) ? pc[2] : pc[3];
    float ph = 6.283185307179586f / (1.0f + __expf(-(vA + b_enc[nph])));
    p0 = ph; pwv = ph; ka = 0.0f;
  }

  const float dtf = 0.03125f, half = 0.015625f;
  const float sixth = (float)(0.03125/6.0);
  const float mscale = (float)(2.0 / (1024.0 * 889.0));     // BETA/N / (7*127)
  const float kscale = (float)(1.0 / 16129.0);              // 1/127^2

  char* a1wr = smem + A1_OFF + nph;   // per-lane feat byte address (constant)

  for (int e = 0; e < 64; ++e) {
    float csv, snv;
    // ---- Phase A: all 64 lanes, 1 phase each; 1 cos + 1 sin byte store
    {
      snv = __sinf(pwv);
      csv = __cosf(pwv);
      *(char*)(a1wr)        = (char)(__float2int_rn(csv*127.0f));
      *(char*)(a1wr + 1024) = (char)(__float2int_rn(snv*127.0f));
    }
    __syncthreads();

    // ---- GEMM1 i8 K=64 with i4 T1 (unpack = AND/SHR, biased +8); 16 MFMA/wave
    {
      const int pt = w & 7, kh = w >> 3;
      i32x4 accC = {0,0,0,0}, accS = {0,0,0,0};
      const char* t1b = T1g + (size_t)(pt*16 + kh*8)*1024 + lane*16;
      const char* a1b = smem + A1_OFF + kh*512 + q*16;
      const unsigned M = 0x0F0F0F0Fu;
      #pragma unroll
      for (int i2 = 0; i2 < 8; ++i2) {
        i32x4 pk = *(const i32x4*)(t1b + (size_t)i2*1024);
        i32x4 ca = { (int)((unsigned)pk[0] & M), (int)(((unsigned)pk[0] >> 4) & M),
                     (int)((unsigned)pk[1] & M), (int)(((unsigned)pk[1] >> 4) & M) };
        i32x4 sa = { (int)((unsigned)pk[2] & M), (int)(((unsigned)pk[2] >> 4) & M),
                     (int)((unsigned)pk[3] & M), (int)(((unsigned)pk[3] >> 4) & M) };
        i32x4 bc = *(const i32x4*)(a1b + i2*64);
        i32x4 bs = *(const i32x4*)(a1b + i2*64 + 1024);
        accC = __builtin_amdgcn_mfma_i32_16x16x64_i8(ca, bc, accC, 0, 0, 0);
        accS = __builtin_amdgcn_mfma_i32_16x16x64_i8(sa, bs, accS, 0, 0, 0);
      }
      if (b16 == 0) {
        i32x4 acc = accC + accS;
        *(i32x4*)(smem + MBUF_OFF + kh*528 + ((pt*16 + q*4) << 2)) = acc;
      }
    }
    __syncthreads();

    // ---- softmax (wave 0): m' = m*889 + 8*Sum(f) (bias p-independent ->
    // softmax shift-invariant); w i8 (x127)
    if (w == 0) {
      const char* mb = smem + MBUF_OFF + lane*8;
      int a0 = *(const int*)(mb),       a1 = *(const int*)(mb + 4);
      int b0 = *(const int*)(mb + 528), b1 = *(const int*)(mb + 528 + 4);
      float e0 = __expf((float)(a0 + b0) * mscale);
      float e1 = __expf((float)(a1 + b1) * mscale);
      float s = e0 + e1;
      #pragma unroll
      for (int off = 1; off < 64; off <<= 1) s += __shfl_xor(s, off, 64);
      const float inv = 127.0f / s;
      int w0 = __float2int_rn(e0 * inv);
      int w1 = __float2int_rn(e1 * inv);
      *(unsigned short*)(smem + W_OFF + lane*2) =
          (unsigned short)((w0 & 255) | (w1 << 8));
    }
    __syncthreads();

    // ---- GEMM2 i8 K=64 + RK4 (unchanged): waves 0..8 LDS, 9..15 global.
    {
      const float swt = tc.s[e], cwt = tc.c[e];
      const int st = e & 3;
      i32x4 wf0 = *(const i32x4*)(smem + W_OFF + q*16);
      i32x4 wf1 = *(const i32x4*)(smem + W_OFF + 64 + q*16);
      i32x4 aC[4] = {{0,0,0,0},{0,0,0,0},{0,0,0,0},{0,0,0,0}};
      i32x4 aS[4] = {{0,0,0,0},{0,0,0,0},{0,0,0,0},{0,0,0,0}};
      if (w < 9) {
        const char* t2b = smem + T2L_OFF + (size_t)(w*8)*2048 + lane*16;
        #pragma unroll
        for (int c = 0; c < 4; ++c)
          #pragma unroll
          for (int P2 = 0; P2 < 2; ++P2) {
            i32x4 ct_ = *(const i32x4*)(t2b + (size_t)(c*2 + P2)*2048);
            i32x4 st_ = *(const i32x4*)(t2b + (size_t)(c*2 + P2)*2048 + 1024);
            i32x4 wf = P2 ? wf1 : wf0;
            aC[c] = __builtin_amdgcn_mfma_i32_16x16x64_i8(ct_, wf, aC[c], 0, 0, 0);
            aS[c] = __builtin_amdgcn_mfma_i32_16x16x64_i8(st_, wf, aS[c], 0, 0, 0);
          }
      } else {
        const char* t2b = T2g + (size_t)(w*8)*2048 + lane*16;
        #pragma unroll
        for (int c = 0; c < 4; ++c)
          #pragma unroll
          for (int P2 = 0; P2 < 2; ++P2) {
            i32x4 ct_ = *(const i32x4*)(t2b + (size_t)(c*2 + P2)*2048);
            i32x4 st_ = *(const i32x4*)(t2b + (size_t)(c*2 + P2)*2048 + 1024);
            i32x4 wf = P2 ? wf1 : wf0;
            aC[c] = __builtin_amdgcn_mfma_i32_16x16x64_i8(ct_, wf, aC[c], 0, 0, 0);
            aS[c] = __builtin_amdgcn_mfma_i32_16x16x64_i8(st_, wf, aS[c], 0, 0, 0);
          }
      }
      i32x4 c4 = (j4==0) ? aC[0] : (j4==1) ? aC[1] : (j4==2) ? aC[2] : aC[3];
      i32x4 s4 = (j4==0) ? aS[0] : (j4==1) ? aS[1] : (j4==2) ? aS[2] : aS[3];
      float vC = (float)((r4==0) ? c4[0] : (r4==1) ? c4[1] : (r4==2) ? c4[2] : c4[3]);
      float vS = (float)((r4==0) ? s4[0] : (r4==1) ? s4[1] : (r4==2) ? s4[2] : s4[3]);
      float kv = (snv*vC - csv*vS) * kscale
               + 0.08f*(swt*csv - cwt*snv);           // A*sin(wt - phi)
      if (st == 0)      { ka  = kv;           pwv = p0 + kv*half; }
      else if (st == 1) { ka += 2.0f*kv;      pwv = p0 + kv*half; }
      else if (st == 2) { ka += 2.0f*kv;      pwv = p0 + kv*dtf;  }
      else { ka += kv; p0 += ka*sixth; pwv = p0; }
    }
  }

  // ---- epilogue (bf16 MFMA): out = [cos phiT, sin phiT] @ W_out^T + b_out
  __syncthreads();
  {
    *(unsigned short*)(smem + A1_OFF + nph*2)        = f2bf(__cosf(p0));
    *(unsigned short*)(smem + A1_OFF + 2048 + nph*2) = f2bf(__sinf(p0));
  }
  __syncthreads();
  {  // D[cl][col] partial over this wave's 4 ktiles; A = W_out rows (cl<10, pad 0)
    f32x4 acc = {0.f, 0.f, 0.f, 0.f};
    #pragma unroll
    for (int i2 = 0; i2 < 4; ++i2) {
      const int kt = w*4 + i2;
      const int k = kt*32 + q*8;
      bf16x8 afr = {0,0,0,0,0,0,0,0};
      if (b16 < 10) {
        f32x4 v0 = *(const f32x4*)(W_out + b16*2048 + k);
        f32x4 v1 = *(const f32x4*)(W_out + b16*2048 + k + 4);
        #pragma unroll
        for (int i = 0; i < 8; ++i) afr[i] = (short)f2bf(i < 4 ? v0[i] : v1[i-4]);
      }
      const char* baddr = (b16 == 0)
          ? (smem + A1_OFF + ((kt*4 + q) << 4))
          : (smem + ZP_OFF);
      bf16x8 bfr = *(const bf16x8*)baddr;
      acc = __builtin_amdgcn_mfma_f32_16x16x32_bf16(afr, bfr, acc, 0, 0, 0);
    }
    *(f32x4*)(smem + RED_OFF + ((w*64 + lane) << 4)) = acc;
  }
  __syncthreads();
  if (tid < 64) {   // reduce 16 wave-partials; lane: col = tid&15, cl = (tid>>4)*4+r
    f32x4 s = {0.f, 0.f, 0.f, 0.f};
    #pragma unroll
    for (int w2 = 0; w2 < 16; ++w2)
      s += *(const f32x4*)(smem + RED_OFF + ((w2*64 + tid) << 4));
    const int b = tid & 15, q2 = tid >> 4;
    if (b == 0) {
      #pragma unroll
      for (int r = 0; r < 4; ++r) {
        const int cl = q2*4 + r;
        if (cl < 10)
          dout[(size_t)bk*10 + cl] = s[r] + b_out[cl];
      }
    }
  }
}

extern "C" void kernel_launch(void* const* d_in, const int* in_sizes, int n_in,
                              void* d_out, int out_size, void* d_ws, size_t ws_size,
                              hipStream_t stream) {
  (void)in_sizes; (void)n_in; (void)ws_size; (void)out_size;
  const float* x     = (const float*)d_in[0];
  const float* W_enc = (const float*)d_in[1];
  const float* b_enc = (const float*)d_in[2];
  const float* xi    = (const float*)d_in[3];
  const float* W_out = (const float*)d_in[4];
  const float* b_out = (const float*)d_in[5];
  float* out = (float*)d_out;
  char* wsb = (char*)d_ws;   // T1 i4 128K @0 | T2 i8 ct>=36 @256K; rewritten per launch

  TCons tc;
  const double OME = 2.0 * 3.14159265358979323846 * 200.0;
  const double dtd = 0.03125;
  const double co[4] = {0.0, 0.5, 0.5, 1.0};
  for (int e = 0; e < 64; ++e) {
    double t = ((double)(e >> 2) + co[e & 3]) * dtd;
    tc.s[e] = (float)sin(OME * t);
    tc.c[e] = (float)cos(OME * t);
  }

  phasenn_kernel<<<dim3(256), dim3(1024), 0, stream>>>(
      x, W_enc, b_enc, xi, W_out, b_out, out, wsb, tc);
}